// Round 6
// baseline (744.278 us; speedup 1.0000x reference)
//
#include <hip/hip_runtime.h>

#define N_NODES 100000
#define N_EDGES 3200000
#define DIM 256

#define BROWS 128                 // rows per bucket
#define NBUCK 782                 // ceil(N_NODES / 128)
#define NCBIN 49                  // col>>11 -> 0..48
#define NPART 16                  // wave partitions (localrow & 15)
#define NKEY (NPART * NCBIN)      // 784 sort keys per bucket

typedef short short8 __attribute__((ext_vector_type(8)));
typedef float f32x4 __attribute__((ext_vector_type(4)));

static __device__ __forceinline__ unsigned short f2bf(float f) {
    unsigned int u = __float_as_uint(f);
    u = (u + 0x7FFFu + ((u >> 16) & 1u)) >> 16;   // RNE
    return (unsigned short)u;
}

// ---------------- bucket counts ----------------
__global__ __launch_bounds__(512) void k_cnt(const int* __restrict__ row,
                                             int* __restrict__ bcnt) {
    __shared__ int h[NBUCK];
    int t = threadIdx.x;
    const int per = N_EDGES / 256;             // 12500
    int e0 = blockIdx.x * per, e1 = e0 + per;
    for (int i = t; i < NBUCK; i += 512) h[i] = 0;
    __syncthreads();
    for (int e = e0 + t; e < e1; e += 512)
        atomicAdd(&h[row[e] >> 7], 1);
    __syncthreads();
    for (int i = t; i < NBUCK; i += 512)
        if (h[i]) atomicAdd(&bcnt[i], h[i]);
}

// exclusive scan of bcnt[782] -> bbase[783], bcur copy. 1 block, 1024 thr.
__global__ __launch_bounds__(1024) void k_scanb(const int* __restrict__ bcnt,
                                                int* __restrict__ bbase,
                                                int* __restrict__ bcur) {
    __shared__ int lds[1024];
    int t = threadIdx.x;
    int x = (t < NBUCK) ? bcnt[t] : 0;
    lds[t] = x;
    __syncthreads();
    for (int off = 1; off < 1024; off <<= 1) {
        int v = (t >= off) ? lds[t - off] : 0;
        __syncthreads();
        lds[t] += v;
        __syncthreads();
    }
    if (t < NBUCK) { int ex = lds[t] - x; bbase[t] = ex; bcur[t] = ex; }
    if (t == 1023) bbase[NBUCK] = lds[1023];   // == N_EDGES
}

// Pass 1: block-local counting scatter into per-(block,bucket) contiguous
// sub-segments of tmp (cache lines assembled within one XCD's L2).
__global__ __launch_bounds__(512) void k_bucket2(const int* __restrict__ row,
                                                 const int* __restrict__ col,
                                                 const float* __restrict__ val,
                                                 int* __restrict__ bcur,
                                                 int2* __restrict__ tmp) {
    __shared__ int hist[NBUCK];
    __shared__ int base[NBUCK];
    int t = threadIdx.x;
    const int per = N_EDGES / 256;             // 12500
    int e0 = blockIdx.x * per, e1 = e0 + per;
    for (int i = t; i < NBUCK; i += 512) hist[i] = 0;
    __syncthreads();
    for (int e = e0 + t; e < e1; e += 512)
        atomicAdd(&hist[row[e] >> 7], 1);
    __syncthreads();
    for (int i = t; i < NBUCK; i += 512) {
        int c = hist[i];
        base[i] = c ? atomicAdd(&bcur[i], c) : 0;
        hist[i] = 0;                           // reuse as local cursor
    }
    __syncthreads();
    for (int e = e0 + t; e < e1; e += 512) {
        int r = row[e];
        int b = r >> 7;
        int off = atomicAdd(&hist[b], 1);
        // pack: col bits [0,17), localrow (0..127) bits [17,24)
        tmp[base[b] + off] = make_int2(((r & 127) << 17) | col[e],
                                       __float_as_int(val[e]));
    }
}

// Pass 2: per-bucket counting sort by key (localrow&15, col>>11) so that
// (a) each wave of k_agg2 owns a disjoint row set (race-free LDS accum) and
// (b) edges are processed in ascending-col order => chip-wide sliding gather
// window over sup that stays L2/L3-resident.
__global__ __launch_bounds__(1024) void k_place2(const int* __restrict__ bbase,
                                                 const int2* __restrict__ tmp,
                                                 int2* __restrict__ csr2,
                                                 int* __restrict__ pstart) {
    __shared__ int h[1024];        // key histogram then inclusive scan
    __shared__ int cur[NKEY];      // scatter cursors
    int t = threadIdx.x;
    int b = blockIdx.x;
    int s = bbase[b], e = bbase[b + 1];
    h[t] = 0;
    __syncthreads();
    for (int i = s + t; i < e; i += 1024) {
        int rx = tmp[i].x;
        int key = ((rx >> 17) & 15) * NCBIN + ((rx & 0x1FFFF) >> 11);
        atomicAdd(&h[key], 1);
    }
    __syncthreads();
    int x = h[t];
    __syncthreads();
    // Hillis-Steele inclusive scan over 1024 (784 live, rest zero)
    for (int off = 1; off < 1024; off <<= 1) {
        int v = (t >= off) ? h[t - off] : 0;
        __syncthreads();
        h[t] += v;
        __syncthreads();
    }
    if (t < NKEY) cur[t] = s + h[t] - x;       // exclusive + bucket base
    __syncthreads();
    if (t < NPART) pstart[b * NPART + t] = cur[t * NCBIN];
    __syncthreads();   // FIX: snapshot cur into pstart BEFORE any scatter bumps it
    for (int i = s + t; i < e; i += 1024) {
        int2 rec = tmp[i];
        int key = ((rec.x >> 17) & 15) * NCBIN + ((rec.x & 0x1FFFF) >> 11);
        int p = atomicAdd(&cur[key], 1);
        csr2[p] = rec;
    }
}

// ---------------- W pack (fp32 -> bf16 fragment layout) ----------------
__global__ void k_wpack(const float* __restrict__ W, unsigned short* __restrict__ wp) {
    int t = blockIdx.x * 256 + threadIdx.x;     // 0..8191
    int lane = t & 63;
    int nt = (t >> 6) & 15;
    int kc = t >> 10;
    int n = nt * 16 + (lane & 15);
    int kbase = kc * 32 + ((lane >> 4) << 3);
    unsigned short* dst = wp + (size_t)t * 8;
#pragma unroll
    for (int j = 0; j < 8; j++) dst[j] = f2bf(W[(size_t)(kbase + j) * DIM + n]);
}

// ---------------- GEMM: sup(bf16) = X @ W, computed as (X@W)^T tiles ----------------
#define LDSTRIDE 528
__global__ __launch_bounds__(1024, 4) void k_gemm(const float* __restrict__ X,
                                                  const unsigned short* __restrict__ wp,
                                                  unsigned short* __restrict__ sup) {
    __shared__ char pool[16 * 16 * LDSTRIDE];   // 135168 B
    unsigned short* wlds = (unsigned short*)pool;
    int t = threadIdx.x;
    int wave = t >> 6, lane = t & 63;
    int q = lane >> 4, nl = lane & 15;

    const int nstrips = (N_NODES + 255) / 256;  // 391
    for (int s = blockIdx.x; s < nstrips; s += gridDim.x) {
        for (int i = t; i < 8192; i += 1024)
            ((uint4*)wlds)[i] = ((const uint4*)wp)[i];
        __syncthreads();

        int rowbase = s * 256 + wave * 16;
        f32x4 acc[16];
#pragma unroll
        for (int mt = 0; mt < 16; mt++) acc[mt] = (f32x4){0.f, 0.f, 0.f, 0.f};

        for (int kc = 0; kc < 8; kc++) {
            int r = rowbase + nl;
            short8 b = (short8)0;
            if (r < N_NODES) {
                const float* bp = X + (size_t)r * DIM + kc * 32 + (q << 3);
                float4 b0 = *(const float4*)bp;
                float4 b1 = *(const float4*)(bp + 4);
                b[0] = (short)f2bf(b0.x); b[1] = (short)f2bf(b0.y);
                b[2] = (short)f2bf(b0.z); b[3] = (short)f2bf(b0.w);
                b[4] = (short)f2bf(b1.x); b[5] = (short)f2bf(b1.y);
                b[6] = (short)f2bf(b1.z); b[7] = (short)f2bf(b1.w);
            }
#pragma unroll
            for (int mt = 0; mt < 16; mt++) {
                short8 a = *(const short8*)&wlds[(size_t)(((kc * 16 + mt) * 64) + lane) * 8];
                acc[mt] = __builtin_amdgcn_mfma_f32_16x16x32_bf16(a, b, acc[mt], 0, 0, 0);
            }
        }
        __syncthreads();

        char* wbase = pool + wave * (16 * LDSTRIDE);
#pragma unroll
        for (int mt = 0; mt < 16; mt++) {
            uint2 p;
            p.x = ((unsigned int)f2bf(acc[mt][1]) << 16) | f2bf(acc[mt][0]);
            p.y = ((unsigned int)f2bf(acc[mt][3]) << 16) | f2bf(acc[mt][2]);
            *(uint2*)(wbase + nl * LDSTRIDE + mt * 32 + q * 8) = p;
        }
#pragma unroll
        for (int i = 0; i < 8; i++) {
            int row = 2 * i + (lane >> 5);
            uint4 v = *(const uint4*)(wbase + row * LDSTRIDE + (lane & 31) * 16);
            int node = rowbase + row;
            if (node < N_NODES)
                *(uint4*)((char*)sup + (size_t)node * 512 + (lane & 31) * 16) = v;
        }
        __syncthreads();
    }
}

// ---------------- aggregation v4: col-sliding-window + LDS row accumulators ----
// One block per 128-row bucket; 16 waves; wave w owns rows with localrow&15==w.
// Edges arrive sorted by (partition, colbin) => each wave's gather stream sweeps
// sup in ascending-col order; all resident blocks sweep together => the active
// gather window is a few MB (L2/L3-resident) instead of the full 51.2 MB.
__global__ __launch_bounds__(1024) void k_agg2(const int* __restrict__ bbase,
                                               const int* __restrict__ pstart,
                                               const int2* __restrict__ csr2,
                                               const unsigned short* __restrict__ sup,
                                               const float* __restrict__ bias,
                                               float* __restrict__ out) {
    __shared__ float acc[BROWS * DIM];          // 128 KB fp32 accumulators
    int t = threadIdx.x;
    int b = blockIdx.x;

    float4* a4 = (float4*)acc;
    for (int i = t; i < BROWS * (DIM / 4); i += 1024)
        a4[i] = make_float4(0.f, 0.f, 0.f, 0.f);
    __syncthreads();

    int w = t >> 6, lane = t & 63;
    int lo = bbase[b], hi = bbase[b + 1];
    int s = pstart[b * NPART + w];
    int e = (w < NPART - 1) ? pstart[b * NPART + w + 1] : hi;
    s = max(s, lo); e = min(e, hi);             // defensive clamp

#pragma unroll 2
    for (int i = s; i < e; ++i) {
        int2 rec = csr2[i];                     // uniform across wave (broadcast)
        int row = (rec.x >> 17) & 127;          // 0..127, row&15 == w guaranteed
        float v = __int_as_float(rec.y);
        const uint2* sp = (const uint2*)(sup + (size_t)(rec.x & 0x1FFFF) * DIM + lane * 4);
        uint2 u = *sp;                          // 8B/lane, 512B/wave contiguous
        float* ap = acc + row * DIM + lane * 4;
        f32x4 a = *(f32x4*)ap;
        a[0] += v * __uint_as_float(u.x << 16);
        a[1] += v * __uint_as_float(u.x & 0xFFFF0000u);
        a[2] += v * __uint_as_float(u.y << 16);
        a[3] += v * __uint_as_float(u.y & 0xFFFF0000u);
        *(f32x4*)ap = a;
    }
    __syncthreads();

    // epilogue: bucket rows are contiguous in out -> fully coalesced 128 KB
    int gr0 = b * BROWS;
    for (int i = t; i < BROWS * (DIM / 4); i += 1024) {
        int lr = i >> 6, c4 = i & 63;
        int gr = gr0 + lr;
        if (gr < N_NODES) {
            float4 bv = ((const float4*)bias)[c4];
            float4 av = a4[i];
            float4 o;
            o.x = av.x + bv.x; o.y = av.y + bv.y;
            o.z = av.z + bv.z; o.w = av.w + bv.w;
            ((float4*)out)[(size_t)gr * 64 + c4] = o;
        }
    }
}

extern "C" void kernel_launch(void* const* d_in, const int* in_sizes, int n_in,
                              void* d_out, int out_size, void* d_ws, size_t ws_size,
                              hipStream_t stream) {
    const float* X    = (const float*)d_in[0];
    const int*   erow = (const int*)d_in[1];
    const int*   ecol = (const int*)d_in[2];
    const float* eval = (const float*)d_in[3];
    const float* W    = (const float*)d_in[4];
    const float* bias = (const float*)d_in[5];
    float* out = (float*)d_out;

    // Workspace: stays strictly inside the verified baseline footprint.
    // Small arrays live in the old rsb region (409600 B).
    char* ws = (char*)d_ws;
    int*            bcnt   = (int*)ws;                        // 782 ints
    int*            bbase  = (int*)(ws + 4096);               // 783 ints
    int*            bcur   = (int*)(ws + 8192);               // 782 ints
    int*            pstart = (int*)(ws + 16384);              // 782*16 ints = 50 KB
    unsigned short* wp     = (unsigned short*)(ws + 823296);  // 65536 bf16
    int2*           csr2   = (int2*)(ws + 954368);            // 3.2M int2 = 25.6 MB
    unsigned short* sup    = (unsigned short*)(ws + 26554368);// 25.6M bf16 = 51.2 MB
    int2*           tmp    = (int2*)(ws + 26554368);          // aliases sup (dead until k_gemm)

    hipMemsetAsync(bcnt, 0, 4096, stream);
    k_cnt<<<256, 512, 0, stream>>>(erow, bcnt);
    k_scanb<<<1, 1024, 0, stream>>>(bcnt, bbase, bcur);
    k_bucket2<<<256, 512, 0, stream>>>(erow, ecol, eval, bcur, tmp);
    k_place2<<<NBUCK, 1024, 0, stream>>>(bbase, tmp, csr2, pstart);
    k_wpack<<<32, 256, 0, stream>>>(W, wp);
    k_gemm<<<256, 1024, 0, stream>>>(X, wp, sup);
    k_agg2<<<NBUCK, 1024, 0, stream>>>(bbase, pstart, csr2, sup, bias, out);
}

// Round 7
// 558.232 us; speedup vs baseline: 1.3333x; 1.3333x over previous
//
#include <hip/hip_runtime.h>

#define N_NODES 100000
#define N_EDGES 3200000
#define DIM 256

#define BROWS 128                 // rows per bucket
#define NBUCK 782                 // ceil(N_NODES / 128)

typedef short short8 __attribute__((ext_vector_type(8)));
typedef float f32x4 __attribute__((ext_vector_type(4)));

static __device__ __forceinline__ unsigned short f2bf(float f) {
    unsigned int u = __float_as_uint(f);
    u = (u + 0x7FFFu + ((u >> 16) & 1u)) >> 16;   // RNE
    return (unsigned short)u;
}

// ---------------- bucket counts (verified R6) ----------------
__global__ __launch_bounds__(512) void k_cnt(const int* __restrict__ row,
                                             int* __restrict__ bcnt) {
    __shared__ int h[NBUCK];
    int t = threadIdx.x;
    const int per = N_EDGES / 256;             // 12500
    int e0 = blockIdx.x * per, e1 = e0 + per;
    for (int i = t; i < NBUCK; i += 512) h[i] = 0;
    __syncthreads();
    for (int e = e0 + t; e < e1; e += 512)
        atomicAdd(&h[row[e] >> 7], 1);
    __syncthreads();
    for (int i = t; i < NBUCK; i += 512)
        if (h[i]) atomicAdd(&bcnt[i], h[i]);
}

// exclusive scan of bcnt[782] -> bbase[783], bcur copy (verified R6).
// Also writes the rs sentinel rs[N_NODES] = N_EDGES.
__global__ __launch_bounds__(1024) void k_scanb(const int* __restrict__ bcnt,
                                                int* __restrict__ bbase,
                                                int* __restrict__ bcur,
                                                int* __restrict__ rs) {
    __shared__ int lds[1024];
    int t = threadIdx.x;
    int x = (t < NBUCK) ? bcnt[t] : 0;
    lds[t] = x;
    __syncthreads();
    for (int off = 1; off < 1024; off <<= 1) {
        int v = (t >= off) ? lds[t - off] : 0;
        __syncthreads();
        lds[t] += v;
        __syncthreads();
    }
    if (t < NBUCK) { int ex = lds[t] - x; bbase[t] = ex; bcur[t] = ex; }
    if (t == 1023) { bbase[NBUCK] = lds[1023]; rs[N_NODES] = N_EDGES; }
}

// Pass 1: block-local counting scatter into per-(block,bucket) contiguous
// sub-segments of tmp — cache lines assembled within one XCD's L2 (verified R6).
__global__ __launch_bounds__(512) void k_bucket2(const int* __restrict__ row,
                                                 const int* __restrict__ col,
                                                 const float* __restrict__ val,
                                                 int* __restrict__ bcur,
                                                 int2* __restrict__ tmp) {
    __shared__ int hist[NBUCK];
    __shared__ int base[NBUCK];
    int t = threadIdx.x;
    const int per = N_EDGES / 256;             // 12500
    int e0 = blockIdx.x * per, e1 = e0 + per;
    for (int i = t; i < NBUCK; i += 512) hist[i] = 0;
    __syncthreads();
    for (int e = e0 + t; e < e1; e += 512)
        atomicAdd(&hist[row[e] >> 7], 1);
    __syncthreads();
    for (int i = t; i < NBUCK; i += 512) {
        int c = hist[i];
        base[i] = c ? atomicAdd(&bcur[i], c) : 0;
        hist[i] = 0;                           // reuse as local cursor
    }
    __syncthreads();
    for (int e = e0 + t; e < e1; e += 512) {
        int r = row[e];
        int b = r >> 7;
        int off = atomicAdd(&hist[b], 1);
        // pack: col bits [0,17), localrow (0..127) bits [17,24)
        tmp[base[b] + off] = make_int2(((r & 127) << 17) | col[e],
                                       __float_as_int(val[e]));
    }
}

// Pass 2: per-bucket counting sort BY ROW (128 keys) -> row-contiguous CSR,
// and emit per-row offsets rs[] = bucket base + intra-bucket exclusive scan.
// This replaces the old per-row k_hist (3.2M random cross-XCD atomics, ~140us)
// + scan1/scan2/scanadd chain entirely.
__global__ __launch_bounds__(1024) void k_place3(const int* __restrict__ bbase,
                                                 const int2* __restrict__ tmp,
                                                 int2* __restrict__ csr,
                                                 int* __restrict__ rs) {
    __shared__ int h[BROWS];
    __shared__ int cur[BROWS];
    int t = threadIdx.x;
    int b = blockIdx.x;
    int s = bbase[b], e = bbase[b + 1];
    if (t < BROWS) h[t] = 0;
    __syncthreads();
    for (int i = s + t; i < e; i += 1024)
        atomicAdd(&h[(tmp[i].x >> 17) & 127], 1);
    __syncthreads();
    int x = (t < BROWS) ? h[t] : 0;
    __syncthreads();
    // Hillis-Steele inclusive scan over 128 (all threads hit the barriers)
    for (int off = 1; off < BROWS; off <<= 1) {
        int v = (t >= off && t < BROWS) ? h[t - off] : 0;
        __syncthreads();
        if (t < BROWS) h[t] += v;
        __syncthreads();
    }
    if (t < BROWS) {
        int ex = s + h[t] - x;                 // bucket base + exclusive
        cur[t] = ex;
        int rr = b * BROWS + t;
        if (rr < N_NODES) rs[rr] = ex;
    }
    __syncthreads();
    for (int i = s + t; i < e; i += 1024) {
        int2 rec = tmp[i];
        int p = atomicAdd(&cur[(rec.x >> 17) & 127], 1);
        csr[p] = make_int2(rec.x & 0x1FFFF, rec.y);
    }
}

// ---------------- W pack (fp32 -> bf16 fragment layout) ----------------
__global__ void k_wpack(const float* __restrict__ W, unsigned short* __restrict__ wp) {
    int t = blockIdx.x * 256 + threadIdx.x;     // 0..8191
    int lane = t & 63;
    int nt = (t >> 6) & 15;
    int kc = t >> 10;
    int n = nt * 16 + (lane & 15);
    int kbase = kc * 32 + ((lane >> 4) << 3);
    unsigned short* dst = wp + (size_t)t * 8;
#pragma unroll
    for (int j = 0; j < 8; j++) dst[j] = f2bf(W[(size_t)(kbase + j) * DIM + n]);
}

// ---------------- GEMM: sup(bf16) = X @ W, computed as (X@W)^T tiles ----------------
#define LDSTRIDE 528
__global__ __launch_bounds__(1024, 4) void k_gemm(const float* __restrict__ X,
                                                  const unsigned short* __restrict__ wp,
                                                  unsigned short* __restrict__ sup) {
    __shared__ char pool[16 * 16 * LDSTRIDE];   // 135168 B
    unsigned short* wlds = (unsigned short*)pool;
    int t = threadIdx.x;
    int wave = t >> 6, lane = t & 63;
    int q = lane >> 4, nl = lane & 15;

    const int nstrips = (N_NODES + 255) / 256;  // 391
    for (int s = blockIdx.x; s < nstrips; s += gridDim.x) {
        for (int i = t; i < 8192; i += 1024)
            ((uint4*)wlds)[i] = ((const uint4*)wp)[i];
        __syncthreads();

        int rowbase = s * 256 + wave * 16;
        f32x4 acc[16];
#pragma unroll
        for (int mt = 0; mt < 16; mt++) acc[mt] = (f32x4){0.f, 0.f, 0.f, 0.f};

        for (int kc = 0; kc < 8; kc++) {
            int r = rowbase + nl;
            short8 b = (short8)0;
            if (r < N_NODES) {
                const float* bp = X + (size_t)r * DIM + kc * 32 + (q << 3);
                float4 b0 = *(const float4*)bp;
                float4 b1 = *(const float4*)(bp + 4);
                b[0] = (short)f2bf(b0.x); b[1] = (short)f2bf(b0.y);
                b[2] = (short)f2bf(b0.z); b[3] = (short)f2bf(b0.w);
                b[4] = (short)f2bf(b1.x); b[5] = (short)f2bf(b1.y);
                b[6] = (short)f2bf(b1.z); b[7] = (short)f2bf(b1.w);
            }
#pragma unroll
            for (int mt = 0; mt < 16; mt++) {
                short8 a = *(const short8*)&wlds[(size_t)(((kc * 16 + mt) * 64) + lane) * 8];
                acc[mt] = __builtin_amdgcn_mfma_f32_16x16x32_bf16(a, b, acc[mt], 0, 0, 0);
            }
        }
        __syncthreads();

        char* wbase = pool + wave * (16 * LDSTRIDE);
#pragma unroll
        for (int mt = 0; mt < 16; mt++) {
            uint2 p;
            p.x = ((unsigned int)f2bf(acc[mt][1]) << 16) | f2bf(acc[mt][0]);
            p.y = ((unsigned int)f2bf(acc[mt][3]) << 16) | f2bf(acc[mt][2]);
            *(uint2*)(wbase + nl * LDSTRIDE + mt * 32 + q * 8) = p;
        }
#pragma unroll
        for (int i = 0; i < 8; i++) {
            int row = 2 * i + (lane >> 5);
            uint4 v = *(const uint4*)(wbase + row * LDSTRIDE + (lane & 31) * 16);
            int node = rowbase + row;
            if (node < N_NODES)
                *(uint4*)((char*)sup + (size_t)node * 512 + (lane & 31) * 16) = v;
        }
        __syncthreads();
    }
}

// ---------------- CSR aggregation (v1, verified R2 @223us) ----------------
// One wave per row. 4 lane-groups of 16 handle 4 edges concurrently;
// each lane covers 16 dims (2x dwordx4 gather). Cross-group combine by shuffle.
__global__ __launch_bounds__(256) void k_agg(const int* __restrict__ rs,
                                             const int2* __restrict__ csr,
                                             const unsigned short* __restrict__ sup,
                                             const float* __restrict__ bias,
                                             float* __restrict__ out) {
    int wave = threadIdx.x >> 6, lane = threadIdx.x & 63;
    int r = blockIdx.x * 4 + wave;
    int s = rs[r], e = rs[r + 1];
    int g = lane >> 4;          // edge subgroup 0..3
    int L = lane & 15;          // dim subgroup: dims [L*16, L*16+16)

    float acc[16];
#pragma unroll
    for (int j = 0; j < 16; j++) acc[j] = 0.f;

    int i = s;
    for (; i + 4 <= e; i += 4) {
        int2 ce = csr[i + g];
        float v = __int_as_float(ce.y);
        const uint4* sp = (const uint4*)(sup + (size_t)ce.x * DIM + L * 16);
        uint4 u0 = sp[0];
        uint4 u1 = sp[1];
        unsigned int uu[8] = {u0.x, u0.y, u0.z, u0.w, u1.x, u1.y, u1.z, u1.w};
#pragma unroll
        for (int k = 0; k < 8; k++) {
            acc[2 * k]     += v * __uint_as_float(uu[k] << 16);
            acc[2 * k + 1] += v * __uint_as_float(uu[k] & 0xFFFF0000u);
        }
    }
    {   // tail (<4 edges)
        int idx = i + g;
        if (idx < e) {
            int2 ce = csr[idx];
            float v = __int_as_float(ce.y);
            const uint4* sp = (const uint4*)(sup + (size_t)ce.x * DIM + L * 16);
            uint4 u0 = sp[0];
            uint4 u1 = sp[1];
            unsigned int uu[8] = {u0.x, u0.y, u0.z, u0.w, u1.x, u1.y, u1.z, u1.w};
#pragma unroll
            for (int k = 0; k < 8; k++) {
                acc[2 * k]     += v * __uint_as_float(uu[k] << 16);
                acc[2 * k + 1] += v * __uint_as_float(uu[k] & 0xFFFF0000u);
            }
        }
    }
    // combine groups: lanes {L, L+16, L+32, L+48} hold same dims
#pragma unroll
    for (int j = 0; j < 16; j++) {
        float x = acc[j];
        x += __shfl_down(x, 32, 64);
        x += __shfl_down(x, 16, 64);
        acc[j] = x;
    }
    if (lane < 16) {
        float4* op = (float4*)(out + (size_t)r * DIM + L * 16);
        const float4* bp = (const float4*)(bias + L * 16);
#pragma unroll
        for (int qq = 0; qq < 4; qq++) {
            float4 b = bp[qq];
            float4 o;
            o.x = acc[4 * qq]     + b.x;
            o.y = acc[4 * qq + 1] + b.y;
            o.z = acc[4 * qq + 2] + b.z;
            o.w = acc[4 * qq + 3] + b.w;
            op[qq] = o;
        }
    }
}

extern "C" void kernel_launch(void* const* d_in, const int* in_sizes, int n_in,
                              void* d_out, int out_size, void* d_ws, size_t ws_size,
                              hipStream_t stream) {
    const float* X    = (const float*)d_in[0];
    const int*   erow = (const int*)d_in[1];
    const int*   ecol = (const int*)d_in[2];
    const float* eval = (const float*)d_in[3];
    const float* W    = (const float*)d_in[4];
    const float* bias = (const float*)d_in[5];
    float* out = (float*)d_out;

    // Workspace: strictly inside the verified baseline footprint.
    // rs: 100001 ints in the old rsb region; bcnt/bbase/bcur in the old cur region.
    char* ws = (char*)d_ws;
    int*            rs    = (int*)ws;                         // 100001 ints (400004 B)
    int*            bcnt  = (int*)(ws + 409600);              // 782 ints
    int*            bbase = (int*)(ws + 413696);              // 783 ints
    int*            bcur  = (int*)(ws + 417792);              // 782 ints
    unsigned short* wp    = (unsigned short*)(ws + 823296);   // 65536 bf16
    int2*           csr   = (int2*)(ws + 954368);             // 3.2M int2 = 25.6 MB
    unsigned short* sup   = (unsigned short*)(ws + 26554368); // 25.6M bf16 = 51.2 MB
    int2*           tmp   = (int2*)(ws + 26554368);           // aliases sup (dead until k_gemm)

    hipMemsetAsync(bcnt, 0, 4096, stream);
    k_cnt<<<256, 512, 0, stream>>>(erow, bcnt);
    k_scanb<<<1, 1024, 0, stream>>>(bcnt, bbase, bcur, rs);
    k_bucket2<<<256, 512, 0, stream>>>(erow, ecol, eval, bcur, tmp);
    k_place3<<<NBUCK, 1024, 0, stream>>>(bbase, tmp, csr, rs);
    k_wpack<<<32, 256, 0, stream>>>(W, wp);
    k_gemm<<<256, 1024, 0, stream>>>(X, wp, sup);
    k_agg<<<N_NODES / 4, 256, 0, stream>>>(rs, csr, sup, bias, out);
}

// Round 8
// 552.244 us; speedup vs baseline: 1.3477x; 1.0108x over previous
//
#include <hip/hip_runtime.h>

#define N_NODES 100000
#define N_EDGES 3200000
#define DIM 256

#define BROWS 128                 // rows per bucket
#define NBUCK 782                 // ceil(N_NODES / 128)
#define CAP   5120                // fixed tmp capacity per bucket (mean 4096, +16 sigma)

typedef short short8 __attribute__((ext_vector_type(8)));
typedef float f32x4 __attribute__((ext_vector_type(4)));

static __device__ __forceinline__ unsigned short f2bf(float f) {
    unsigned int u = __float_as_uint(f);
    u = (u + 0x7FFFu + ((u >> 16) & 1u)) >> 16;   // RNE
    return (unsigned short)u;
}

// Pass 1: block-local counting scatter into per-(block,bucket) contiguous
// sub-segments of tmp (fixed per-bucket stride CAP — no global scan needed).
// Cache lines assembled within one XCD's L2 (pattern verified R6/R7).
__global__ __launch_bounds__(512) void k_bucket2(const int* __restrict__ row,
                                                 const int* __restrict__ col,
                                                 const float* __restrict__ val,
                                                 int* __restrict__ bcur,
                                                 int2* __restrict__ tmp) {
    __shared__ int hist[NBUCK];
    __shared__ int base[NBUCK];   // absolute tmp index of this block's sub-segment
    int t = threadIdx.x;
    const int per = N_EDGES / 256;             // 12500
    int e0 = blockIdx.x * per, e1 = e0 + per;
    for (int i = t; i < NBUCK; i += 512) hist[i] = 0;
    __syncthreads();
    for (int e = e0 + t; e < e1; e += 512)
        atomicAdd(&hist[row[e] >> 7], 1);
    __syncthreads();
    for (int i = t; i < NBUCK; i += 512) {
        int c = hist[i];
        base[i] = c ? (i * CAP + atomicAdd(&bcur[i], c)) : 0;
        hist[i] = 0;                           // reuse as local cursor
    }
    __syncthreads();
    for (int e = e0 + t; e < e1; e += 512) {
        int r = row[e];
        int b = r >> 7;
        int off = atomicAdd(&hist[b], 1);
        // pack: col bits [0,17), localrow (0..127) bits [17,24)
        tmp[base[b] + off] = make_int2(((r & 127) << 17) | col[e],
                                       __float_as_int(val[e]));
    }
}

// Pass 2: per-bucket counting sort BY ROW (128 keys) -> row-contiguous CSR.
// Bucket's compact csr range reserved with ONE global atomic (order in csr is
// arbitrary; k_agg indexes only through rs/re). Emits per-row [rs, re).
__global__ __launch_bounds__(1024) void k_place3(const int* __restrict__ bcur,
                                                 const int2* __restrict__ tmp,
                                                 int2* __restrict__ csr,
                                                 int* __restrict__ rs,
                                                 int* __restrict__ re,
                                                 int* __restrict__ gcur) {
    __shared__ int h[BROWS];
    __shared__ int cur[BROWS];
    __shared__ int gb;
    int t = threadIdx.x;
    int b = blockIdx.x;
    int cnt = bcur[b];
    const int2* tb = tmp + (size_t)b * CAP;
    if (t < BROWS) h[t] = 0;
    __syncthreads();
    for (int i = t; i < cnt; i += 1024)
        atomicAdd(&h[(tb[i].x >> 17) & 127], 1);
    __syncthreads();
    int x = (t < BROWS) ? h[t] : 0;
    __syncthreads();
    // Hillis-Steele inclusive scan over 128 (all threads hit the barriers)
    for (int off = 1; off < BROWS; off <<= 1) {
        int v = (t >= off && t < BROWS) ? h[t - off] : 0;
        __syncthreads();
        if (t < BROWS) h[t] += v;
        __syncthreads();
    }
    if (t == 0) gb = atomicAdd(gcur, cnt);
    __syncthreads();
    if (t < BROWS) {
        int inc = h[t];                        // inclusive count
        int ex = gb + inc - x;                 // exclusive start
        cur[t] = ex;
        int rr = b * BROWS + t;
        if (rr < N_NODES) { rs[rr] = ex; re[rr] = gb + inc; }
    }
    __syncthreads();
    for (int i = t; i < cnt; i += 1024) {
        int2 rec = tb[i];
        int p = atomicAdd(&cur[(rec.x >> 17) & 127], 1);
        csr[p] = make_int2(rec.x & 0x1FFFF, rec.y);
    }
}

// ---------------- W pack (fp32 -> bf16 fragment layout) ----------------
__global__ void k_wpack(const float* __restrict__ W, unsigned short* __restrict__ wp) {
    int t = blockIdx.x * 256 + threadIdx.x;     // 0..8191
    int lane = t & 63;
    int nt = (t >> 6) & 15;
    int kc = t >> 10;
    int n = nt * 16 + (lane & 15);
    int kbase = kc * 32 + ((lane >> 4) << 3);
    unsigned short* dst = wp + (size_t)t * 8;
#pragma unroll
    for (int j = 0; j < 8; j++) dst[j] = f2bf(W[(size_t)(kbase + j) * DIM + n]);
}

// ---------------- GEMM: sup(bf16) = X @ W, computed as (X@W)^T tiles ----------------
#define LDSTRIDE 528
__global__ __launch_bounds__(1024, 4) void k_gemm(const float* __restrict__ X,
                                                  const unsigned short* __restrict__ wp,
                                                  unsigned short* __restrict__ sup) {
    __shared__ char pool[16 * 16 * LDSTRIDE];   // 135168 B
    unsigned short* wlds = (unsigned short*)pool;
    int t = threadIdx.x;
    int wave = t >> 6, lane = t & 63;
    int q = lane >> 4, nl = lane & 15;

    const int nstrips = (N_NODES + 255) / 256;  // 391
    for (int s = blockIdx.x; s < nstrips; s += gridDim.x) {
        for (int i = t; i < 8192; i += 1024)
            ((uint4*)wlds)[i] = ((const uint4*)wp)[i];
        __syncthreads();

        int rowbase = s * 256 + wave * 16;
        f32x4 acc[16];
#pragma unroll
        for (int mt = 0; mt < 16; mt++) acc[mt] = (f32x4){0.f, 0.f, 0.f, 0.f};

        for (int kc = 0; kc < 8; kc++) {
            int r = rowbase + nl;
            short8 b = (short8)0;
            if (r < N_NODES) {
                const float* bp = X + (size_t)r * DIM + kc * 32 + (q << 3);
                float4 b0 = *(const float4*)bp;
                float4 b1 = *(const float4*)(bp + 4);
                b[0] = (short)f2bf(b0.x); b[1] = (short)f2bf(b0.y);
                b[2] = (short)f2bf(b0.z); b[3] = (short)f2bf(b0.w);
                b[4] = (short)f2bf(b1.x); b[5] = (short)f2bf(b1.y);
                b[6] = (short)f2bf(b1.z); b[7] = (short)f2bf(b1.w);
            }
#pragma unroll
            for (int mt = 0; mt < 16; mt++) {
                short8 a = *(const short8*)&wlds[(size_t)(((kc * 16 + mt) * 64) + lane) * 8];
                acc[mt] = __builtin_amdgcn_mfma_f32_16x16x32_bf16(a, b, acc[mt], 0, 0, 0);
            }
        }
        __syncthreads();

        char* wbase = pool + wave * (16 * LDSTRIDE);
#pragma unroll
        for (int mt = 0; mt < 16; mt++) {
            uint2 p;
            p.x = ((unsigned int)f2bf(acc[mt][1]) << 16) | f2bf(acc[mt][0]);
            p.y = ((unsigned int)f2bf(acc[mt][3]) << 16) | f2bf(acc[mt][2]);
            *(uint2*)(wbase + nl * LDSTRIDE + mt * 32 + q * 8) = p;
        }
#pragma unroll
        for (int i = 0; i < 8; i++) {
            int row = 2 * i + (lane >> 5);
            uint4 v = *(const uint4*)(wbase + row * LDSTRIDE + (lane & 31) * 16);
            int node = rowbase + row;
            if (node < N_NODES)
                *(uint4*)((char*)sup + (size_t)node * 512 + (lane & 31) * 16) = v;
        }
        __syncthreads();
    }
}

// ---------------- CSR aggregation (v1, verified R2/R7 @221-223us) ----------------
// One wave per row. 4 lane-groups of 16 handle 4 edges concurrently;
// each lane covers 16 dims (2x dwordx4 gather). Cross-group combine by shuffle.
__global__ __launch_bounds__(256) void k_agg(const int* __restrict__ rs,
                                             const int* __restrict__ re,
                                             const int2* __restrict__ csr,
                                             const unsigned short* __restrict__ sup,
                                             const float* __restrict__ bias,
                                             float* __restrict__ out) {
    int wave = threadIdx.x >> 6, lane = threadIdx.x & 63;
    int r = blockIdx.x * 4 + wave;
    int s = rs[r], e = re[r];
    int g = lane >> 4;          // edge subgroup 0..3
    int L = lane & 15;          // dim subgroup: dims [L*16, L*16+16)

    float acc[16];
#pragma unroll
    for (int j = 0; j < 16; j++) acc[j] = 0.f;

    int i = s;
    for (; i + 4 <= e; i += 4) {
        int2 ce = csr[i + g];
        float v = __int_as_float(ce.y);
        const uint4* sp = (const uint4*)(sup + (size_t)ce.x * DIM + L * 16);
        uint4 u0 = sp[0];
        uint4 u1 = sp[1];
        unsigned int uu[8] = {u0.x, u0.y, u0.z, u0.w, u1.x, u1.y, u1.z, u1.w};
#pragma unroll
        for (int k = 0; k < 8; k++) {
            acc[2 * k]     += v * __uint_as_float(uu[k] << 16);
            acc[2 * k + 1] += v * __uint_as_float(uu[k] & 0xFFFF0000u);
        }
    }
    {   // tail (<4 edges)
        int idx = i + g;
        if (idx < e) {
            int2 ce = csr[idx];
            float v = __int_as_float(ce.y);
            const uint4* sp = (const uint4*)(sup + (size_t)ce.x * DIM + L * 16);
            uint4 u0 = sp[0];
            uint4 u1 = sp[1];
            unsigned int uu[8] = {u0.x, u0.y, u0.z, u0.w, u1.x, u1.y, u1.z, u1.w};
#pragma unroll
            for (int k = 0; k < 8; k++) {
                acc[2 * k]     += v * __uint_as_float(uu[k] << 16);
                acc[2 * k + 1] += v * __uint_as_float(uu[k] & 0xFFFF0000u);
            }
        }
    }
    // combine groups: lanes {L, L+16, L+32, L+48} hold same dims
#pragma unroll
    for (int j = 0; j < 16; j++) {
        float x = acc[j];
        x += __shfl_down(x, 32, 64);
        x += __shfl_down(x, 16, 64);
        acc[j] = x;
    }
    if (lane < 16) {
        float4* op = (float4*)(out + (size_t)r * DIM + L * 16);
        const float4* bp = (const float4*)(bias + L * 16);
#pragma unroll
        for (int qq = 0; qq < 4; qq++) {
            float4 b = bp[qq];
            float4 o;
            o.x = acc[4 * qq]     + b.x;
            o.y = acc[4 * qq + 1] + b.y;
            o.z = acc[4 * qq + 2] + b.z;
            o.w = acc[4 * qq + 3] + b.w;
            op[qq] = o;
        }
    }
}

extern "C" void kernel_launch(void* const* d_in, const int* in_sizes, int n_in,
                              void* d_out, int out_size, void* d_ws, size_t ws_size,
                              hipStream_t stream) {
    const float* X    = (const float*)d_in[0];
    const int*   erow = (const int*)d_in[1];
    const int*   ecol = (const int*)d_in[2];
    const float* eval = (const float*)d_in[3];
    const float* W    = (const float*)d_in[4];
    const float* bias = (const float*)d_in[5];
    float* out = (float*)d_out;

    // Workspace: strictly inside the verified baseline footprint.
    char* ws = (char*)d_ws;
    int*            rs    = (int*)ws;                         // 100000 ints (old rsb region)
    int*            re    = (int*)(ws + 409600);              // 100000 ints (old cur region)
    int*            bcur  = (int*)(ws + 819200);              // 782 ints (old bsum region)
    int*            gcur  = (int*)(ws + 822400);              // 1 int
    unsigned short* wp    = (unsigned short*)(ws + 823296);   // 65536 bf16
    int2*           csr   = (int2*)(ws + 954368);             // 3.2M int2 = 25.6 MB (compact)
    unsigned short* sup   = (unsigned short*)(ws + 26554368); // 25.6M bf16 = 51.2 MB
    int2*           tmp   = (int2*)(ws + 26554368);           // aliases sup; 782*5120*8 = 32.0 MB <= 51.2

    hipMemsetAsync(bcur, 0, 4096, stream);    // zeroes bcur + gcur
    k_bucket2<<<256, 512, 0, stream>>>(erow, ecol, eval, bcur, tmp);
    k_place3<<<NBUCK, 1024, 0, stream>>>(bcur, tmp, csr, rs, re, gcur);
    k_wpack<<<32, 256, 0, stream>>>(W, wp);
    k_gemm<<<256, 1024, 0, stream>>>(X, wp, sup);
    k_agg<<<N_NODES / 4, 256, 0, stream>>>(rs, re, csr, sup, bias, out);
}